// Round 10
// baseline (56.885 us; speedup 1.0000x reference)
//
#include <hip/hip_runtime.h>
#include <hip/hip_bf16.h>

#define DN 128
#define DE 64
#define NN 512

typedef __bf16 bf16x8 __attribute__((ext_vector_type(8)));
typedef float  f32x4  __attribute__((ext_vector_type(4)));

// -------- fused prep: 4 node-rows per 256-thread block ----------------------
// blocks 0..255: rows bid*4+w -> rms_norm(nodes)*g_node, rp = nn@Wr + b,
//                cp = nn@Wc.   block 256 (wave 0): pack g_edge*We into bf16
//                fragment order, k-map k = kh*32 + (e>>2)*16 + kg*4 + (e&3).
__global__ __launch_bounds__(256) void prep_kernel(
    const float* __restrict__ nodes, const float* __restrict__ g_node,
    const float* __restrict__ g_edge, const float* __restrict__ W,
    const float* __restrict__ bias, float* __restrict__ rp,
    float* __restrict__ cp, __bf16* __restrict__ weg) {
    const int w = threadIdx.x >> 6;
    const int l = threadIdx.x & 63;
    if (blockIdx.x == 256) {
        if (w != 0) return;
        const int kg = l >> 4;
        for (int kh = 0; kh < 2; ++kh)
            for (int ct = 0; ct < 4; ++ct) {
                const int f = kh * 4 + ct;
                #pragma unroll
                for (int e = 0; e < 8; ++e) {
                    const int k   = kh * 32 + (e >> 2) * 16 + kg * 4 + (e & 3);
                    const int col = ct * 16 + (l & 15);
                    weg[(f * 64 + l) * 8 + e] =
                        (__bf16)(g_edge[k] * W[(2 * DN + k) * DE + col]);
                }
            }
        return;
    }
    const int row = blockIdx.x * 4 + w;   // b*N + i
    __shared__ float nn[4][DN];

    float x0 = nodes[row * DN + l];
    float x1 = nodes[row * DN + l + 64];
    float ssq = x0 * x0 + x1 * x1;
    #pragma unroll
    for (int m = 1; m < 64; m <<= 1) ssq += __shfl_xor(ssq, m, 64);
    float scale = rsqrtf(ssq * (1.0f / DN) + 1.1920929e-7f);
    nn[w][l]      = x0 * scale * g_node[l];
    nn[w][l + 64] = x1 * scale * g_node[l + 64];
    __syncthreads();

    float accr = bias[l];
    float accc = 0.0f;
    #pragma unroll 4
    for (int d = 0; d < DN; ++d) {
        float nd = nn[w][d];
        accr += nd * W[d * DE + l];          // Wr = W[0:128]
        accc += nd * W[(DN + d) * DE + l];   // Wc = W[128:256]
    }
    rp[row * DE + l] = accr;
    cp[row * DE + l] = accc;
}

// -------- main: R9 structure, 2 tiles per wave (prologue amortized) ---------
// grid 4096 x 256, zero __syncthreads, wave-independent. row = bid>>2,
// wave w owns j in [(bid&3)*128 + w*32, +32) = 2 tiles of 16 rows, each with
// its own 4 KB LDS buffer (no cross-tile hazard; compiler free to overlap
// tile-1 loads with tile-0 compute — no sched pinning). Global loads/stores
// plain ascending dwordx4 (copy-identical); XOR swizzle on the LDS side;
// final stores NONTEMPORAL full-line (keeps edges L3-resident).
__global__ __launch_bounds__(256, 4) void main_kernel(
    const float* __restrict__ edges, const float* __restrict__ rp,
    const float* __restrict__ cp, const __bf16* __restrict__ weg,
    float* __restrict__ out) {
    __shared__ float lds[8192];            // 32 KB; wave w: [w*2048, +2048)
    const int bid = blockIdx.x;            // 0..4095
    const int row = bid >> 2;              // b*N + i
    const int t4  = threadIdx.x;           // 0..255
    const int w   = t4 >> 6;
    const int l   = t4 & 63;
    const int r16 = l & 15;
    const int kg  = l >> 4;
    const int jb  = (bid & 3) * 128 + w * 32;  // wave j-base (2 tiles)
    const int bN  = (row >> 9) << 9;       // b*512

    float* wlds = &lds[w * 2048];
    const float* tbase = edges + ((size_t)row * NN + jb) * DE;
    float*       obase = out   + ((size_t)row * NN + jb) * DE;

    // ---- hoisted reg operands (amortized over 2 tiles) ----
    bf16x8 wf[8];
    #pragma unroll
    for (int f = 0; f < 8; ++f)
        wf[f] = *reinterpret_cast<const bf16x8*>(weg + (f * 64 + l) * 8);

    f32x4 rpv[4];
    #pragma unroll
    for (int c = 0; c < 4; ++c)
        rpv[c] = *reinterpret_cast<const f32x4*>(rp + row * DE + c * 16 + kg * 4);

    #pragma unroll
    for (int t = 0; t < 2; ++t) {
        float* tl = &wlds[t * 1024];             // this tile's 4 KB buffer
        const int fo = t * 1024;                 // float offset of tile in stream

        // ---- P1: plain ascending loads (copy-identical) ----
        f32x4 st[4];
        #pragma unroll
        for (int i = 0; i < 4; ++i)
            st[i] = *reinterpret_cast<const f32x4*>(tbase + fo + (i * 64 + l) * 4);

        const int j = jb + t * 16 + r16;         // this lane's global j
        const float* cprow = cp + (size_t)(bN + j) * DE + kg * 4;
        f32x4 cpv[4];
        #pragma unroll
        for (int c = 0; c < 4; ++c)
            cpv[c] = *reinterpret_cast<const f32x4*>(cprow + c * 16);

        // ---- P2: staged regs -> LDS, swizzled dest (chunk c of row r -> c^r) ----
        #pragma unroll
        for (int i = 0; i < 4; ++i) {
            const int C = i * 64 + l;
            const int r = C >> 4;
            const int q = (C & 15) ^ r;
            *reinterpret_cast<f32x4*>(&tl[r * 64 + q * 4]) = st[i];
        }

        // ---- P3: fragments (swizzled reads; wave-local ordering) ----
        f32x4 x[4];
        #pragma unroll
        for (int m = 0; m < 4; ++m) {
            const int q = (m * 4 + kg) ^ r16;
            x[m] = *reinterpret_cast<const f32x4*>(&tl[r16 * 64 + q * 4]);
        }

        float ssq = 0.0f;
        #pragma unroll
        for (int m = 0; m < 4; ++m)
            #pragma unroll
            for (int e = 0; e < 4; ++e) ssq += x[m][e] * x[m][e];
        ssq += __shfl_xor(ssq, 16, 64);
        ssq += __shfl_xor(ssq, 32, 64);
        const float scale = rsqrtf(ssq * (1.0f / DE) + 1.1920929e-7f);

        bf16x8 a0, a1;
        #pragma unroll
        for (int e = 0; e < 4; ++e) {
            a0[e]     = (__bf16)x[0][e];   // k = kg*4+e
            a0[e + 4] = (__bf16)x[1][e];   // k = 16+kg*4+e
            a1[e]     = (__bf16)x[2][e];   // k = 32+kg*4+e
            a1[e + 4] = (__bf16)x[3][e];   // k = 48+kg*4+e
        }

        #pragma unroll
        for (int c = 0; c < 4; ++c) {
            f32x4 z = {0.f, 0.f, 0.f, 0.f};
            z = __builtin_amdgcn_mfma_f32_16x16x32_bf16(wf[c],     a0, z, 0, 0, 0);
            z = __builtin_amdgcn_mfma_f32_16x16x32_bf16(wf[4 + c], a1, z, 0, 0, 0);
            f32x4 o;
            #pragma unroll
            for (int r = 0; r < 4; ++r)
                o[r] = z[r] * scale + rpv[c][r] + cpv[c][r];
            const int qo = (c * 4 + kg) ^ r16;   // swizzled LDS write-back
            *reinterpret_cast<f32x4*>(&tl[r16 * 64 + qo * 4]) = o;
        }

        // ---- P5: swizzled LDS read -> NONTEMPORAL ascending full-line stores ----
        #pragma unroll
        for (int i = 0; i < 4; ++i) {
            const int C = i * 64 + l;
            const int r = C >> 4;
            const int q = (C & 15) ^ r;
            f32x4 v = *reinterpret_cast<const f32x4*>(&tl[r * 64 + q * 4]);
            __builtin_nontemporal_store(v,
                reinterpret_cast<f32x4*>(obase + fo + (i * 64 + l) * 4));
        }
    }
}

extern "C" void kernel_launch(void* const* d_in, const int* in_sizes, int n_in,
                              void* d_out, int out_size, void* d_ws, size_t ws_size,
                              hipStream_t stream) {
    const float* edges  = (const float*)d_in[0];
    const float* nodes  = (const float*)d_in[1];
    const float* g_node = (const float*)d_in[2];
    const float* g_edge = (const float*)d_in[3];
    const float* W      = (const float*)d_in[4];
    const float* bias   = (const float*)d_in[5];
    float* out = (float*)d_out;

    float*  rp  = (float*)d_ws;                 // 1024*64 f32 = 256 KB
    float*  cp  = rp + 1024 * DE;               // 256 KB
    __bf16* weg = (__bf16*)(cp + 1024 * DE);    // 8*64*8 bf16 = 8 KB

    prep_kernel<<<dim3(257), dim3(256), 0, stream>>>(nodes, g_node, g_edge, W,
                                                     bias, rp, cp, weg);
    main_kernel<<<dim3(4096), dim3(256), 0, stream>>>(edges, rp, cp, weg, out);
}